// Round 11
// baseline (428.378 us; speedup 1.0000x reference)
//
#include <hip/hip_runtime.h>

#define HEADS 4
#define EPS 1e-16f
#define NR 256    // dst ranges (counting-sort buckets)
#define EPB 2048  // edges per scatter block

typedef float floatx2 __attribute__((ext_vector_type(2)));

// exact dst-range classifier: q = dst / rdiv (float approx + integer fix)
__device__ inline int rangeOf(int dst, int rdiv, float rinv) {
    int q = (int)((float)dst * rinv);
    if (q > NR - 1) q = NR - 1;
    if ((long long)q * rdiv > dst) --q;
    else if ((long long)(q + 1) * rdiv <= dst) ++q;
    return q;
}

// ==== CSR 1: per-(block,range) counts. LDS atomics only ===================
__global__ __launch_bounds__(256) void scatter_count(
    const int* __restrict__ ei, int E, int rdiv, float rinv,
    int* __restrict__ pcnt)
{
    __shared__ int cnt[NR];
    int b = blockIdx.x, t = threadIdx.x;
    int b0 = b * EPB;
    int nloc = min(EPB, E - b0);
    cnt[t] = 0;
    __syncthreads();
    #pragma unroll
    for (int u = 0; u < 8; ++u) {
        int li = u * 256 + t;
        if (li < nloc)
            atomicAdd(&cnt[rangeOf(ei[E + b0 + li], rdiv, rinv)], 1);
    }
    __syncthreads();
    pcnt[(size_t)b * NR + t] = cnt[t];
}

// ==== CSR 2: per-range prefix over blocks (pcnt -> within-range offsets) ==
__global__ __launch_bounds__(256) void qprefix(
    int* __restrict__ pcnt, int nb, int* __restrict__ qtot)
{
    __shared__ int part[256];
    int q = blockIdx.x, t = threadIdx.x;
    int per = (nb + 255) >> 8;
    int lo = t * per, hi = min(lo + per, nb);
    int s = 0;
    for (int b = lo; b < hi; ++b) s += pcnt[(size_t)b * NR + q];
    part[t] = s;
    __syncthreads();
    for (int off = 1; off < 256; off <<= 1) {
        int a = (t >= off) ? part[t - off] : 0;
        __syncthreads();
        part[t] += a;
        __syncthreads();
    }
    if (t == 255) qtot[q] = part[255];
    int pre = (t == 0) ? 0 : part[t - 1];
    for (int b = lo; b < hi; ++b) {
        int c = pcnt[(size_t)b * NR + q];
        pcnt[(size_t)b * NR + q] = pre;
        pre += c;
    }
}

// ==== CSR 3: scan 256 range totals -> rstart[NR+1] ========================
__global__ void qscan(const int* __restrict__ qtot, int* __restrict__ rstart)
{
    __shared__ int tmp[NR];
    int t = threadIdx.x;
    tmp[t] = qtot[t];
    __syncthreads();
    for (int off = 1; off < NR; off <<= 1) {
        int a = (t >= off) ? tmp[t - off] : 0;
        __syncthreads();
        tmp[t] += a;
        __syncthreads();
    }
    rstart[t] = (t == 0) ? 0 : tmp[t - 1];
    if (t == NR - 1) rstart[NR] = tmp[NR - 1];
}

// ==== CSR 4: place edges into range-grouped SoA. No global atomics ========
__global__ __launch_bounds__(256) void scatter_place(
    const int* __restrict__ ei, int E, int rdiv, float rinv,
    const int* __restrict__ pcnt, const int* __restrict__ rstart,
    int* __restrict__ rsrc, int* __restrict__ rdst)
{
    __shared__ int2 lrec[EPB];
    __shared__ unsigned char lq[EPB];
    __shared__ int cnt[NR], base[NR], scn[NR];
    int b = blockIdx.x, t = threadIdx.x;
    int b0 = b * EPB;
    int nloc = min(EPB, E - b0);
    cnt[t] = 0;
    __syncthreads();
    int myq[8], myoff[8];
    int2 myrec[8];
    #pragma unroll
    for (int u = 0; u < 8; ++u) {
        int li = u * 256 + t;
        if (li < nloc) {
            int e = b0 + li;
            int sv = ei[e], dv = ei[E + e];
            int q = rangeOf(dv, rdiv, rinv);
            myq[u] = q;
            myrec[u] = make_int2(sv, dv);
            myoff[u] = atomicAdd(&cnt[q], 1);
        } else myq[u] = -1;
    }
    __syncthreads();
    scn[t] = cnt[t];
    __syncthreads();
    for (int off = 1; off < 256; off <<= 1) {
        int a = (t >= off) ? scn[t - off] : 0;
        __syncthreads();
        scn[t] += a;
        __syncthreads();
    }
    base[t] = (t == 0) ? 0 : scn[t - 1];
    __syncthreads();
    #pragma unroll
    for (int u = 0; u < 8; ++u) {
        if (myq[u] >= 0) {
            int slot = base[myq[u]] + myoff[u];
            lrec[slot] = myrec[u];
            lq[slot] = (unsigned char)myq[u];
        }
    }
    __syncthreads();
    #pragma unroll
    for (int u = 0; u < 8; ++u) {
        int s2 = u * 256 + t;
        if (s2 < nloc) {
            int q = lq[s2];
            int g = rstart[q] + pcnt[(size_t)b * NR + q] + (s2 - base[q]);
            int2 r = lrec[s2];
            rsrc[g] = r.x;
            rdst[g] = r.y;
        }
    }
}

// ==== CSR 5: per-range degree hist + in-range scan -> row_ptr + deg-bins ==
// Also emits the per-range degree-bin histogram (phd) for the degree sort,
// reusing the in-LDS degrees (saves 2 kernels + 2 passes over deg).
__global__ __launch_bounds__(256) void deg_range(
    const int* __restrict__ rdst, const int* __restrict__ rstart,
    int* __restrict__ deg, int* __restrict__ row_ptr,
    int* __restrict__ phd, int n, int rdiv, int E)
{
    __shared__ int h[512];
    __shared__ int psum[256];
    __shared__ int hd[256];
    int q = blockIdx.x, t = threadIdx.x;
    int lo = q * rdiv, hi = min(lo + rdiv, n);
    int nn = hi - lo;
    if (nn <= 0) {
        phd[q * 256 + t] = 0;
        if (t == 0 && q == NR - 1) row_ptr[n] = E;
        return;
    }
    h[t] = 0; h[t + 256] = 0; hd[t] = 0;
    __syncthreads();
    int rlo = rstart[q], rhi = rstart[q + 1];
    for (int i = rlo + t; i < rhi; i += 256)
        atomicAdd(&h[rdst[i] - lo], 1);
    __syncthreads();
    int s0 = h[2 * t], s1 = h[2 * t + 1];
    psum[t] = s0 + s1;
    __syncthreads();
    for (int off = 1; off < 256; off <<= 1) {
        int a = (t >= off) ? psum[t - off] : 0;
        __syncthreads();
        psum[t] += a;
        __syncthreads();
    }
    int base = rlo + ((t == 0) ? 0 : psum[t - 1]);
    if (2 * t < nn) {
        row_ptr[lo + 2 * t] = base;
        deg[lo + 2 * t] = s0;
        atomicAdd(&hd[min(s0, 255)], 1);
    }
    if (2 * t + 1 < nn) {
        row_ptr[lo + 2 * t + 1] = base + s0;
        deg[lo + 2 * t + 1] = s1;
        atomicAdd(&hd[min(s1, 255)], 1);
    }
    if (t == 0 && q == NR - 1) row_ptr[n] = E;
    __syncthreads();
    phd[q * 256 + t] = hd[t];
}

// ==== degree sort: scan 256x256 bin counts -> per-(range,bin) bases =======
__global__ __launch_bounds__(256) void dsort_prefix(
    int* __restrict__ phd, int nbd)
{
    __shared__ int tot[256];
    int t = threadIdx.x;
    int s = 0;
    for (int b = 0; b < nbd; ++b) s += phd[b * 256 + t];
    tot[t] = s;
    __syncthreads();
    for (int off = 1; off < 256; off <<= 1) {
        int a = (t >= off) ? tot[t - off] : 0;
        __syncthreads();
        tot[t] += a;
        __syncthreads();
    }
    int running = (t == 0) ? 0 : tot[t - 1];
    for (int b = 0; b < nbd; ++b) {
        int c = phd[b * 256 + t];
        phd[b * 256 + t] = running;
        running += c;
    }
}

// ==== CSR 6: per-range placement of col[] AND order[] via LDS cursors =====
__global__ __launch_bounds__(256) void place_range(
    const int* __restrict__ rsrc, const int* __restrict__ rdst,
    const int* __restrict__ rstart, const int* __restrict__ row_ptr,
    const int* __restrict__ deg, const int* __restrict__ phd,
    int* __restrict__ col, int* __restrict__ order, int n, int rdiv)
{
    __shared__ int cur[512];
    __shared__ int lcur[256];
    int q = blockIdx.x, t = threadIdx.x;
    int lo = q * rdiv, hi = min(lo + rdiv, n);
    int nn = hi - lo;
    if (nn <= 0) return;
    for (int i = t; i < nn; i += 256) cur[i] = row_ptr[lo + i];
    lcur[t] = phd[q * 256 + t];
    __syncthreads();
    int rlo = rstart[q], rhi = rstart[q + 1];
    for (int i = rlo + t; i < rhi; i += 256) {
        int pos = atomicAdd(&cur[rdst[i] - lo], 1);
        col[pos] = rsrc[i];
    }
    for (int i = t; i < nn; i += 256) {
        int pos = atomicAdd(&lcur[min(deg[lo + i], 255)], 1);
        order[pos] = lo + i;
    }
}

// ================= conv1: fused QKVS projection (128 -> 4x32) =============
// Column-split: bid&1 selects cols 0-63 (Q|K) or 64-127 (V|S).
// LDS = 32KB (W half) + 16KB (32 x-rows) = 48KB -> 3 blocks/CU.
// Thread = 2 rows x 4 cols; scalar-x broadcast + b128 W reads.
__global__ __launch_bounds__(256) void proj1_kernel(
    const float* __restrict__ x,
    const float* __restrict__ Wq, const float* __restrict__ bq,
    const float* __restrict__ Wk, const float* __restrict__ bk,
    const float* __restrict__ Wv, const float* __restrict__ bv,
    const float* __restrict__ Ws, const float* __restrict__ bs,
    float* __restrict__ qs1, unsigned char* __restrict__ kv1, int n)
{
    __shared__ float Wl[128][64];
    __shared__ float xl[32][128];
    int half = blockIdx.x & 1;
    for (int i = threadIdx.x; i < 128 * 64; i += 256) {
        int k = i >> 6, c = i & 63;
        int gc = half * 64 + c;
        int sub = gc >> 5, j = gc & 31;
        const float* W = (sub == 0) ? Wq : (sub == 1) ? Wk : (sub == 2) ? Wv : Ws;
        Wl[k][c] = W[k * 32 + j];
    }
    int col4 = (threadIdx.x & 15) * 4;       // within the 64-col half
    int gcol4 = half * 64 + col4;
    int sub = gcol4 >> 5, j = gcol4 & 31;
    float4 bias4;
    {
        const float* b = (sub == 0) ? bq : (sub == 1) ? bk : (sub == 2) ? bv : bs;
        bias4 = *(const float4*)(b + j);
    }
    int rb = (threadIdx.x >> 4) * 2;         // 0,2,..,30
    __syncthreads();
    int rstride = (gridDim.x >> 1) * 32;
    for (int row0 = (blockIdx.x >> 1) * 32; row0 < n; row0 += rstride) {
        #pragma unroll
        for (int u = 0; u < 4; ++u) {
            int i = threadIdx.x + u * 256;
            int r = i >> 5, c4 = (i & 31) * 4;
            int gr = row0 + r;
            float4 xv = (gr < n) ? *(const float4*)(x + (size_t)gr * 128 + c4)
                                 : make_float4(0.f, 0.f, 0.f, 0.f);
            *(float4*)(&xl[r][c4]) = xv;
        }
        __syncthreads();
        float4 a0 = bias4, a1 = bias4;
        #pragma unroll 8
        for (int k = 0; k < 128; ++k) {
            float4 w = *(const float4*)(&Wl[k][col4]);
            float x0 = xl[rb + 0][k], x1 = xl[rb + 1][k];
            a0.x += x0 * w.x; a0.y += x0 * w.y; a0.z += x0 * w.z; a0.w += x0 * w.w;
            a1.x += x1 * w.x; a1.y += x1 * w.y; a1.z += x1 * w.z; a1.w += x1 * w.w;
        }
        #pragma unroll
        for (int r = 0; r < 2; ++r) {
            int row = row0 + rb + r;
            if (row < n) {
                float4 acc = (r == 0) ? a0 : a1;
                if (sub == 0)
                    *(float4*)(qs1 + (size_t)row * 64 + j) = acc;
                else if (sub == 3)
                    *(float4*)(qs1 + (size_t)row * 64 + 32 + j) = acc;
                else {
                    unsigned u8 = __builtin_amdgcn_cvt_pk_fp8_f32(acc.x, acc.y, 0u, false);
                    u8 = __builtin_amdgcn_cvt_pk_fp8_f32(acc.z, acc.w, u8, true);
                    *(unsigned*)(kv1 + (size_t)row * 64 + ((sub == 1) ? 0 : 32) + j) = u8;
                }
            }
        }
        __syncthreads();
    }
}

// ================= conv2 projection (32 -> 4x16) ==========================
// Outputs: qs2[N][32] fp32 (q|s), kv2[N][32] fp8 e4m3 (k|v, 32B/node)
__global__ __launch_bounds__(256) void proj2_kernel(
    const float* __restrict__ h1,
    const float* __restrict__ Wq, const float* __restrict__ bq,
    const float* __restrict__ Wk, const float* __restrict__ bk,
    const float* __restrict__ Wv, const float* __restrict__ bv,
    const float* __restrict__ Ws, const float* __restrict__ bs,
    float* __restrict__ qs2, unsigned char* __restrict__ kv2, int n)
{
    __shared__ float Wl[32][64];
    __shared__ float bl[64];
    __shared__ float xl[4][32];
    for (int i = threadIdx.x; i < 32 * 64; i += 256) {
        int k = i >> 6, c = i & 63;
        int sub = c >> 4, j = c & 15;
        const float* W = (sub == 0) ? Wq : (sub == 1) ? Wk : (sub == 2) ? Wv : Ws;
        Wl[k][c] = W[k * 16 + j];
    }
    if (threadIdx.x < 64) {
        int c = threadIdx.x, sub = c >> 4, j = c & 15;
        const float* b = (sub == 0) ? bq : (sub == 1) ? bk : (sub == 2) ? bv : bs;
        bl[c] = b[j];
    }
    __syncthreads();
    int r = threadIdx.x >> 6, col = threadIdx.x & 63;
    int sub = col >> 4, j = col & 15;
    for (int row0 = blockIdx.x * 4; row0 < n; row0 += gridDim.x * 4) {
        int li = threadIdx.x;
        if (li < 128) {
            int rr = row0 + (li >> 5);
            if (rr < n) xl[li >> 5][li & 31] = h1[(size_t)rr * 32 + (li & 31)];
        }
        __syncthreads();
        int row = row0 + r;
        if (row < n) {
            float acc = bl[col];
            #pragma unroll
            for (int k = 0; k < 32; ++k) acc += xl[r][k] * Wl[k][col];
            if (sub == 0)       qs2[(size_t)row * 32 + j] = acc;
            else if (sub == 3)  qs2[(size_t)row * 32 + 16 + j] = acc;
            else {
                unsigned u8 = __builtin_amdgcn_cvt_pk_fp8_f32(acc, 0.f, 0u, false);
                kv2[(size_t)row * 32 + ((sub == 1) ? 0 : 16) + j] = (unsigned char)(u8 & 0xFF);
            }
        }
        __syncthreads();
    }
}

// ===== conv1 fused gather: degree-sorted, fp8 KV, 1-deep pipeline =========
__global__ __launch_bounds__(256) void gather_conv1(
    const int* __restrict__ row_ptr, const int* __restrict__ order,
    const int* __restrict__ col, const float* __restrict__ qs1,
    const unsigned char* __restrict__ kv1, float* __restrict__ h1, int n)
{
    int tid = blockIdx.x * 256 + threadIdx.x;
    if (tid >= n * HEADS) return;
    int node = order[tid >> 2], h = tid & 3;
    const float4* qp = (const float4*)(qs1 + (size_t)node * 64 + h * 8);
    float4 q0 = qp[0], q1 = qp[1];
    int start = row_ptr[node], d = row_ptr[node + 1] - start;
    float m = -INFINITY, s = 0.f;
    float a0x=0,a0y=0,a0z=0,a0w=0,a1x=0,a1y=0,a1z=0,a1w=0;
    uint2 ku = make_uint2(0,0), vu = make_uint2(0,0);
    if (d > 0) {
        const unsigned char* b0 = kv1 + (size_t)col[start] * 64;
        ku = *(const uint2*)(b0 + h * 8);
        vu = *(const uint2*)(b0 + 32 + h * 8);
    }
    for (int i = 0; i < d; ++i) {
        uint2 kn = ku, vn = vu;
        if (i + 1 < d) {
            const unsigned char* nb = kv1 + (size_t)col[start + i + 1] * 64;
            kn = *(const uint2*)(nb + h * 8);
            vn = *(const uint2*)(nb + 32 + h * 8);
        }
        floatx2 k01 = __builtin_amdgcn_cvt_pk_f32_fp8(ku.x, false);
        floatx2 k23 = __builtin_amdgcn_cvt_pk_f32_fp8(ku.x, true);
        floatx2 k45 = __builtin_amdgcn_cvt_pk_f32_fp8(ku.y, false);
        floatx2 k67 = __builtin_amdgcn_cvt_pk_f32_fp8(ku.y, true);
        float a = (q0.x*k01.x + q0.y*k01.y + q0.z*k23.x + q0.w*k23.y
                 + q1.x*k45.x + q1.y*k45.y + q1.z*k67.x + q1.w*k67.y)
                * 0.35355339059327373f;  // 1/sqrt(8)
        float mn = fmaxf(m, a);
        float corr = __expf(m - mn);   // first iter: exp(-inf)=0
        float ea = __expf(a - mn);
        s = s * corr + ea;
        floatx2 v01 = __builtin_amdgcn_cvt_pk_f32_fp8(vu.x, false);
        floatx2 v23 = __builtin_amdgcn_cvt_pk_f32_fp8(vu.x, true);
        floatx2 v45 = __builtin_amdgcn_cvt_pk_f32_fp8(vu.y, false);
        floatx2 v67 = __builtin_amdgcn_cvt_pk_f32_fp8(vu.y, true);
        a0x = a0x*corr + ea*v01.x; a0y = a0y*corr + ea*v01.y;
        a0z = a0z*corr + ea*v23.x; a0w = a0w*corr + ea*v23.y;
        a1x = a1x*corr + ea*v45.x; a1y = a1y*corr + ea*v45.y;
        a1z = a1z*corr + ea*v67.x; a1w = a1w*corr + ea*v67.y;
        m = mn;
        ku = kn; vu = vn;
    }
    float inv = 1.f / (s + EPS);
    const float* sk = qs1 + (size_t)node * 64 + 32 + h * 8;
    float4 o0, o1;
    o0.x = fmaxf(a0x*inv + sk[0], 0.f); o0.y = fmaxf(a0y*inv + sk[1], 0.f);
    o0.z = fmaxf(a0z*inv + sk[2], 0.f); o0.w = fmaxf(a0w*inv + sk[3], 0.f);
    o1.x = fmaxf(a1x*inv + sk[4], 0.f); o1.y = fmaxf(a1y*inv + sk[5], 0.f);
    o1.z = fmaxf(a1z*inv + sk[6], 0.f); o1.w = fmaxf(a1w*inv + sk[7], 0.f);
    float4* op = (float4*)(h1 + (size_t)node * 32 + h * 8);
    op[0] = o0; op[1] = o1;
}

// ===== conv2 fused gather (C=4), degree-sorted order, fp8 KV ==============
__global__ __launch_bounds__(256) void gather_conv2(
    const int* __restrict__ row_ptr, const int* __restrict__ order,
    const int* __restrict__ col, const float* __restrict__ qs2,
    const unsigned char* __restrict__ kv2, float* __restrict__ h2, int n)
{
    int tid = blockIdx.x * 256 + threadIdx.x;
    if (tid >= n * HEADS) return;
    int node = order[tid >> 2], h = tid & 3;
    float4 q = *(const float4*)(qs2 + (size_t)node * 32 + h * 4);
    int start = row_ptr[node], d = row_ptr[node + 1] - start;
    float m = -INFINITY, s = 0.f;
    float ax=0, ay=0, az=0, aw=0;
    unsigned ku = 0, vu = 0;
    if (d > 0) {
        const unsigned char* b0 = kv2 + (size_t)col[start] * 32;
        ku = *(const unsigned*)(b0 + h * 4);
        vu = *(const unsigned*)(b0 + 16 + h * 4);
    }
    for (int i = 0; i < d; ++i) {
        unsigned kn = ku, vn = vu;
        if (i + 1 < d) {
            const unsigned char* nb = kv2 + (size_t)col[start + i + 1] * 32;
            kn = *(const unsigned*)(nb + h * 4);
            vn = *(const unsigned*)(nb + 16 + h * 4);
        }
        floatx2 k01 = __builtin_amdgcn_cvt_pk_f32_fp8(ku, false);
        floatx2 k23 = __builtin_amdgcn_cvt_pk_f32_fp8(ku, true);
        float a = (q.x*k01.x + q.y*k01.y + q.z*k23.x + q.w*k23.y) * 0.5f; // 1/sqrt(4)
        float mn = fmaxf(m, a);
        float corr = __expf(m - mn);
        float ea = __expf(a - mn);
        s = s * corr + ea;
        floatx2 v01 = __builtin_amdgcn_cvt_pk_f32_fp8(vu, false);
        floatx2 v23 = __builtin_amdgcn_cvt_pk_f32_fp8(vu, true);
        ax = ax*corr + ea*v01.x; ay = ay*corr + ea*v01.y;
        az = az*corr + ea*v23.x; aw = aw*corr + ea*v23.y;
        m = mn;
        ku = kn; vu = vn;
    }
    float inv = 1.f / (s + EPS);
    const float* sk = qs2 + (size_t)node * 32 + 16 + h * 4;
    float4 o;
    o.x = fmaxf(ax*inv + sk[0], 0.f);
    o.y = fmaxf(ay*inv + sk[1], 0.f);
    o.z = fmaxf(az*inv + sk[2], 0.f);
    o.w = fmaxf(aw*inv + sk[3], 0.f);
    *(float4*)(h2 + (size_t)node * 16 + h * 4) = o;
}

// ====== mean-pool accumulation over h2 (block-local reduce, batch sorted) =
__global__ __launch_bounds__(256) void pool_kernel(
    const float* __restrict__ h2, const int* __restrict__ batch,
    float* __restrict__ pooled, float* __restrict__ cnt, int n)
{
    __shared__ float acc[16];
    __shared__ int bShared;
    __shared__ int uniform;
    int node0 = blockIdx.x * 16;
    int t = threadIdx.x;
    int node = node0 + (t >> 4), j = t & 15;
    if (t == 0) {
        int bFirst = batch[node0];
        int bLast = batch[min(node0 + 15, n - 1)];
        bShared = bFirst;
        uniform = (bFirst == bLast);
    }
    if (t < 16) acc[t] = 0.f;
    __syncthreads();
    bool active = node < n;
    float val = active ? h2[(size_t)node * 16 + j] : 0.f;
    if (uniform) {
        if (active) atomicAdd(&acc[j], val);
        __syncthreads();
        int nlocal = min(16, n - node0);
        if (t < 16) atomicAdd(pooled + bShared * 16 + t, acc[t]);
        if (t == 0) atomicAdd(cnt + bShared, (float)nlocal);
    } else {
        if (active) {
            int b = batch[node];
            atomicAdd(pooled + b * 16 + j, val);
            if (j == 0) atomicAdd(cnt + b, 1.f);
        }
    }
}

// ================= final FC on pooled [64,16] -> [64,10] ==================
__global__ void fc_kernel(
    const float* __restrict__ pooled, const float* __restrict__ cnt,
    const float* __restrict__ Wfc, const float* __restrict__ bfc,
    float* __restrict__ out)
{
    int t = threadIdx.x;
    if (t < 64 * 10) {
        int b = t / 10, o = t % 10;
        float c = fmaxf(cnt[b], 1.0f);
        float acc = bfc[o];
        #pragma unroll
        for (int k = 0; k < 16; ++k)
            acc += (pooled[b * 16 + k] / c) * Wfc[k * 10 + o];
        out[t] = acc;
    }
}

extern "C" void kernel_launch(void* const* d_in, const int* in_sizes, int n_in,
                              void* d_out, int out_size, void* d_ws, size_t ws_size,
                              hipStream_t stream) {
    const float* x     = (const float*)d_in[0];
    const int*   ei    = (const int*)d_in[1];
    const int*   batch = (const int*)d_in[2];
    const float* Wq1 = (const float*)d_in[3],  *bq1 = (const float*)d_in[4];
    const float* Wk1 = (const float*)d_in[5],  *bk1 = (const float*)d_in[6];
    const float* Wv1 = (const float*)d_in[7],  *bv1 = (const float*)d_in[8];
    const float* Ws1 = (const float*)d_in[9],  *bs1 = (const float*)d_in[10];
    const float* Wq2 = (const float*)d_in[11], *bq2 = (const float*)d_in[12];
    const float* Wk2 = (const float*)d_in[13], *bk2 = (const float*)d_in[14];
    const float* Wv2 = (const float*)d_in[15], *bv2 = (const float*)d_in[16];
    const float* Ws2 = (const float*)d_in[17], *bs2 = (const float*)d_in[18];
    const float* Wfc = (const float*)d_in[19], *bfc = (const float*)d_in[20];

    int N = in_sizes[0] / 128;
    int E = in_sizes[1] / 2;
    int rdiv = (N + NR - 1) / NR;            // 391 nodes per range
    float rinv = 1.0f / (float)rdiv;
    int NB = (E + EPB - 1) / EPB;            // scatter blocks

    // ---- workspace layout ----
    float* ws = (float*)d_ws;
    float* qs1    = ws;                                   // N*64 f  (q|s conv1)
    float* h1     = qs1 + (size_t)N * 64;                 // N*32 f  (aliased rsrc)
    float* h2     = h1 + (size_t)N * 32;                  // N*16 f  (aliased rdst lo)
    float* qs2    = h2 + (size_t)N * 16;                  // N*32 f  (rdst overflow)
    float* pooled = qs2 + (size_t)N * 32;                 // 1024 f
    float* cnt    = pooled + 1024;                        // 64 f
    unsigned char* kv1 = (unsigned char*)(cnt + 64);      // N*64 fp8 (64B/node)
    unsigned char* kv2 = kv1 + (size_t)N * 64;            // N*32 fp8 (32B/node)
    int* deg     = (int*)(kv2 + (size_t)N * 32);          // N
    int* row_ptr = deg + N;                               // N+1 (sentinel)
    int* rstart  = row_ptr + N + 1;                       // NR+1
    int* qtot    = rstart + NR + 1;                       // NR
    int* col     = qtot + NR;                             // E
    int* order   = col + E;                               // N
    int* pcnt    = order + N;                             // NB*NR
    int* phd     = pcnt + (size_t)NB * NR;                // NR*256
    int* rsrc = (int*)h1;                                 // E ints (N*32 == E)
    int* rdst = (int*)h2;                                 // E ints (spills into qs2)

    // zero: pooled + cnt accumulators only (everything else fully written)
    hipMemsetAsync(pooled, 0, (1024 + 64) * sizeof(float), stream);

    int ngrid = (N * HEADS + 255) / 256;

    // ---- CSR build + fused degree sort (LDS atomics only) ----
    scatter_count<<<NB, 256, 0, stream>>>(ei, E, rdiv, rinv, pcnt);
    qprefix<<<NR, 256, 0, stream>>>(pcnt, NB, qtot);
    qscan<<<1, NR, 0, stream>>>(qtot, rstart);
    scatter_place<<<NB, 256, 0, stream>>>(ei, E, rdiv, rinv, pcnt, rstart, rsrc, rdst);
    deg_range<<<NR, 256, 0, stream>>>(rdst, rstart, deg, row_ptr, phd, N, rdiv, E);
    dsort_prefix<<<1, 256, 0, stream>>>(phd, NR);
    place_range<<<NR, 256, 0, stream>>>(rsrc, rdst, rstart, row_ptr, deg, phd, col, order, N, rdiv);

    // ---- conv1 ----
    proj1_kernel<<<2048, 256, 0, stream>>>(x, Wq1, bq1, Wk1, bk1, Wv1, bv1, Ws1, bs1, qs1, kv1, N);
    gather_conv1<<<ngrid, 256, 0, stream>>>(row_ptr, order, col, qs1, kv1, h1, N);

    // ---- conv2 ----
    proj2_kernel<<<1024, 256, 0, stream>>>(h1, Wq2, bq2, Wk2, bk2, Wv2, bv2, Ws2, bs2, qs2, kv2, N);
    gather_conv2<<<ngrid, 256, 0, stream>>>(row_ptr, order, col, qs2, kv2, h2, N);

    // ---- pool + fc ----
    pool_kernel<<<(N + 15) / 16, 256, 0, stream>>>(h2, batch, pooled, cnt, N);
    fc_kernel<<<1, 640, 0, stream>>>(pooled, cnt, Wfc, bfc, (float*)d_out);
}

// Round 12
// 372.620 us; speedup vs baseline: 1.1496x; 1.1496x over previous
//
#include <hip/hip_runtime.h>

#define HEADS 4
#define EPS 1e-16f
#define NR 256    // dst ranges (counting-sort buckets)
#define EPB 2048  // edges per scatter block
#define XPAD 132  // xl row stride (132 mod 32 = 4 -> 2-way max on 4-row reads)

typedef float floatx2 __attribute__((ext_vector_type(2)));

// exact dst-range classifier: q = dst / rdiv (float approx + integer fix)
__device__ inline int rangeOf(int dst, int rdiv, float rinv) {
    int q = (int)((float)dst * rinv);
    if (q > NR - 1) q = NR - 1;
    if ((long long)q * rdiv > dst) --q;
    else if ((long long)(q + 1) * rdiv <= dst) ++q;
    return q;
}

// ==== CSR 1: per-(block,range) counts. LDS atomics only ===================
__global__ __launch_bounds__(256) void scatter_count(
    const int* __restrict__ ei, int E, int rdiv, float rinv,
    int* __restrict__ pcnt)
{
    __shared__ int cnt[NR];
    int b = blockIdx.x, t = threadIdx.x;
    int b0 = b * EPB;
    int nloc = min(EPB, E - b0);
    cnt[t] = 0;
    __syncthreads();
    #pragma unroll
    for (int u = 0; u < 8; ++u) {
        int li = u * 256 + t;
        if (li < nloc)
            atomicAdd(&cnt[rangeOf(ei[E + b0 + li], rdiv, rinv)], 1);
    }
    __syncthreads();
    pcnt[(size_t)b * NR + t] = cnt[t];
}

// ==== CSR 2: per-range prefix over blocks (pcnt -> within-range offsets) ==
__global__ __launch_bounds__(256) void qprefix(
    int* __restrict__ pcnt, int nb, int* __restrict__ qtot)
{
    __shared__ int part[256];
    int q = blockIdx.x, t = threadIdx.x;
    int per = (nb + 255) >> 8;
    int lo = t * per, hi = min(lo + per, nb);
    int s = 0;
    for (int b = lo; b < hi; ++b) s += pcnt[(size_t)b * NR + q];
    part[t] = s;
    __syncthreads();
    for (int off = 1; off < 256; off <<= 1) {
        int a = (t >= off) ? part[t - off] : 0;
        __syncthreads();
        part[t] += a;
        __syncthreads();
    }
    if (t == 255) qtot[q] = part[255];
    int pre = (t == 0) ? 0 : part[t - 1];
    for (int b = lo; b < hi; ++b) {
        int c = pcnt[(size_t)b * NR + q];
        pcnt[(size_t)b * NR + q] = pre;
        pre += c;
    }
}

// ==== CSR 3: scan 256 range totals -> rstart[NR+1] ========================
__global__ void qscan(const int* __restrict__ qtot, int* __restrict__ rstart)
{
    __shared__ int tmp[NR];
    int t = threadIdx.x;
    tmp[t] = qtot[t];
    __syncthreads();
    for (int off = 1; off < NR; off <<= 1) {
        int a = (t >= off) ? tmp[t - off] : 0;
        __syncthreads();
        tmp[t] += a;
        __syncthreads();
    }
    rstart[t] = (t == 0) ? 0 : tmp[t - 1];
    if (t == NR - 1) rstart[NR] = tmp[NR - 1];
}

// ==== CSR 4: place edges into range-grouped SoA. No global atomics ========
__global__ __launch_bounds__(256) void scatter_place(
    const int* __restrict__ ei, int E, int rdiv, float rinv,
    const int* __restrict__ pcnt, const int* __restrict__ rstart,
    int* __restrict__ rsrc, int* __restrict__ rdst)
{
    __shared__ int2 lrec[EPB];
    __shared__ unsigned char lq[EPB];
    __shared__ int cnt[NR], base[NR], scn[NR];
    int b = blockIdx.x, t = threadIdx.x;
    int b0 = b * EPB;
    int nloc = min(EPB, E - b0);
    cnt[t] = 0;
    __syncthreads();
    int myq[8], myoff[8];
    int2 myrec[8];
    #pragma unroll
    for (int u = 0; u < 8; ++u) {
        int li = u * 256 + t;
        if (li < nloc) {
            int e = b0 + li;
            int sv = ei[e], dv = ei[E + e];
            int q = rangeOf(dv, rdiv, rinv);
            myq[u] = q;
            myrec[u] = make_int2(sv, dv);
            myoff[u] = atomicAdd(&cnt[q], 1);
        } else myq[u] = -1;
    }
    __syncthreads();
    scn[t] = cnt[t];
    __syncthreads();
    for (int off = 1; off < 256; off <<= 1) {
        int a = (t >= off) ? scn[t - off] : 0;
        __syncthreads();
        scn[t] += a;
        __syncthreads();
    }
    base[t] = (t == 0) ? 0 : scn[t - 1];
    __syncthreads();
    #pragma unroll
    for (int u = 0; u < 8; ++u) {
        if (myq[u] >= 0) {
            int slot = base[myq[u]] + myoff[u];
            lrec[slot] = myrec[u];
            lq[slot] = (unsigned char)myq[u];
        }
    }
    __syncthreads();
    #pragma unroll
    for (int u = 0; u < 8; ++u) {
        int s2 = u * 256 + t;
        if (s2 < nloc) {
            int q = lq[s2];
            int g = rstart[q] + pcnt[(size_t)b * NR + q] + (s2 - base[q]);
            int2 r = lrec[s2];
            rsrc[g] = r.x;
            rdst[g] = r.y;
        }
    }
}

// ==== CSR 5: per-range degree hist + in-range scan -> row_ptr + deg-bins ==
__global__ __launch_bounds__(256) void deg_range(
    const int* __restrict__ rdst, const int* __restrict__ rstart,
    int* __restrict__ deg, int* __restrict__ row_ptr,
    int* __restrict__ phd, int n, int rdiv, int E)
{
    __shared__ int h[512];
    __shared__ int psum[256];
    __shared__ int hd[256];
    int q = blockIdx.x, t = threadIdx.x;
    int lo = q * rdiv, hi = min(lo + rdiv, n);
    int nn = hi - lo;
    if (nn <= 0) {
        phd[q * 256 + t] = 0;
        if (t == 0 && q == NR - 1) row_ptr[n] = E;
        return;
    }
    h[t] = 0; h[t + 256] = 0; hd[t] = 0;
    __syncthreads();
    int rlo = rstart[q], rhi = rstart[q + 1];
    for (int i = rlo + t; i < rhi; i += 256)
        atomicAdd(&h[rdst[i] - lo], 1);
    __syncthreads();
    int s0 = h[2 * t], s1 = h[2 * t + 1];
    psum[t] = s0 + s1;
    __syncthreads();
    for (int off = 1; off < 256; off <<= 1) {
        int a = (t >= off) ? psum[t - off] : 0;
        __syncthreads();
        psum[t] += a;
        __syncthreads();
    }
    int base = rlo + ((t == 0) ? 0 : psum[t - 1]);
    if (2 * t < nn) {
        row_ptr[lo + 2 * t] = base;
        deg[lo + 2 * t] = s0;
        atomicAdd(&hd[min(s0, 255)], 1);
    }
    if (2 * t + 1 < nn) {
        row_ptr[lo + 2 * t + 1] = base + s0;
        deg[lo + 2 * t + 1] = s1;
        atomicAdd(&hd[min(s1, 255)], 1);
    }
    if (t == 0 && q == NR - 1) row_ptr[n] = E;
    __syncthreads();
    phd[q * 256 + t] = hd[t];
}

// ==== degree sort A: per-bin scan over ranges (256 blocks, parallel) ======
// phd[q][bin] -> exclusive prefix over q within bin; tot[bin] = bin total
__global__ __launch_bounds__(256) void dsort_scanA(
    int* __restrict__ phd, int* __restrict__ tot)
{
    __shared__ int tmp[256];
    int bin = blockIdx.x, t = threadIdx.x;
    int v = phd[t * 256 + bin];
    tmp[t] = v;
    __syncthreads();
    for (int off = 1; off < 256; off <<= 1) {
        int a = (t >= off) ? tmp[t - off] : 0;
        __syncthreads();
        tmp[t] += a;
        __syncthreads();
    }
    phd[t * 256 + bin] = tmp[t] - v;     // exclusive within-bin
    if (t == 255) tot[bin] = tmp[255];
}

// ==== degree sort B: exclusive scan of 256 bin totals (1 tiny block) ======
__global__ void dsort_scanB(int* __restrict__ tot)
{
    __shared__ int tmp[256];
    int t = threadIdx.x;
    int v = tot[t];
    tmp[t] = v;
    __syncthreads();
    for (int off = 1; off < 256; off <<= 1) {
        int a = (t >= off) ? tmp[t - off] : 0;
        __syncthreads();
        tmp[t] += a;
        __syncthreads();
    }
    tot[t] = tmp[t] - v;                 // exclusive bin base
}

// ==== degree sort C: add bin base into per-(range,bin) cursor =============
__global__ __launch_bounds__(256) void dsort_addC(
    int* __restrict__ phd, const int* __restrict__ tot)
{
    int t = threadIdx.x;
    phd[blockIdx.x * 256 + t] += tot[t];
}

// ==== CSR 6: per-range placement of col[] AND order[] via LDS cursors =====
__global__ __launch_bounds__(256) void place_range(
    const int* __restrict__ rsrc, const int* __restrict__ rdst,
    const int* __restrict__ rstart, const int* __restrict__ row_ptr,
    const int* __restrict__ deg, const int* __restrict__ phd,
    int* __restrict__ col, int* __restrict__ order, int n, int rdiv)
{
    __shared__ int cur[512];
    __shared__ int lcur[256];
    int q = blockIdx.x, t = threadIdx.x;
    int lo = q * rdiv, hi = min(lo + rdiv, n);
    int nn = hi - lo;
    if (nn <= 0) return;
    for (int i = t; i < nn; i += 256) cur[i] = row_ptr[lo + i];
    lcur[t] = phd[q * 256 + t];
    __syncthreads();
    int rlo = rstart[q], rhi = rstart[q + 1];
    for (int i = rlo + t; i < rhi; i += 256) {
        int pos = atomicAdd(&cur[rdst[i] - lo], 1);
        col[pos] = rsrc[i];
    }
    for (int i = t; i < nn; i += 256) {
        int pos = atomicAdd(&lcur[min(deg[lo + i], 255)], 1);
        order[pos] = lo + i;
    }
}

// ================= conv1: fused QKVS projection (128 -> 4x32) =============
// Column-split (bid&1): 64 cols/block. 64 rows staged, padded xl.
// Thread = 4 rows x 4 cols; k-blocked b128 reads; LDS 66KB -> 2 blocks/CU.
__global__ __launch_bounds__(256) void proj1_kernel(
    const float* __restrict__ x,
    const float* __restrict__ Wq, const float* __restrict__ bq,
    const float* __restrict__ Wk, const float* __restrict__ bk,
    const float* __restrict__ Wv, const float* __restrict__ bv,
    const float* __restrict__ Ws, const float* __restrict__ bs,
    float* __restrict__ qs1, unsigned char* __restrict__ kv1, int n)
{
    __shared__ float Wl[128][64];
    __shared__ float xl[64][XPAD];
    int half = blockIdx.x & 1;
    for (int i = threadIdx.x; i < 128 * 64; i += 256) {
        int k = i >> 6, c = i & 63;
        int gc = half * 64 + c;
        int sub = gc >> 5, j = gc & 31;
        const float* W = (sub == 0) ? Wq : (sub == 1) ? Wk : (sub == 2) ? Wv : Ws;
        Wl[k][c] = W[k * 32 + j];
    }
    int col4 = (threadIdx.x & 15) * 4;       // 16 col-groups in the 64-col half
    int gcol4 = half * 64 + col4;
    int sub = gcol4 >> 5, j = gcol4 & 31;
    float4 bias4;
    {
        const float* b = (sub == 0) ? bq : (sub == 1) ? bk : (sub == 2) ? bv : bs;
        bias4 = *(const float4*)(b + j);
    }
    int rb = (threadIdx.x >> 4) * 4;         // 0,4,..,60
    __syncthreads();
    int rstride = (gridDim.x >> 1) * 64;
    for (int row0 = (blockIdx.x >> 1) * 64; row0 < n; row0 += rstride) {
        #pragma unroll
        for (int u = 0; u < 8; ++u) {
            int i = threadIdx.x + u * 256;   // 0..2047 float4 slots
            int r = i >> 5, c4 = (i & 31) * 4;
            int gr = row0 + r;
            float4 xv = (gr < n) ? *(const float4*)(x + (size_t)gr * 128 + c4)
                                 : make_float4(0.f, 0.f, 0.f, 0.f);
            *(float4*)(&xl[r][c4]) = xv;
        }
        __syncthreads();
        float4 a0 = bias4, a1 = bias4, a2 = bias4, a3 = bias4;
        #pragma unroll 2
        for (int k = 0; k < 128; k += 4) {
            float4 xv0 = *(const float4*)(&xl[rb + 0][k]);
            float4 xv1 = *(const float4*)(&xl[rb + 1][k]);
            float4 xv2 = *(const float4*)(&xl[rb + 2][k]);
            float4 xv3 = *(const float4*)(&xl[rb + 3][k]);
            float4 w0 = *(const float4*)(&Wl[k + 0][col4]);
            float4 w1 = *(const float4*)(&Wl[k + 1][col4]);
            float4 w2 = *(const float4*)(&Wl[k + 2][col4]);
            float4 w3 = *(const float4*)(&Wl[k + 3][col4]);
            a0.x += xv0.x*w0.x + xv0.y*w1.x + xv0.z*w2.x + xv0.w*w3.x;
            a0.y += xv0.x*w0.y + xv0.y*w1.y + xv0.z*w2.y + xv0.w*w3.y;
            a0.z += xv0.x*w0.z + xv0.y*w1.z + xv0.z*w2.z + xv0.w*w3.z;
            a0.w += xv0.x*w0.w + xv0.y*w1.w + xv0.z*w2.w + xv0.w*w3.w;
            a1.x += xv1.x*w0.x + xv1.y*w1.x + xv1.z*w2.x + xv1.w*w3.x;
            a1.y += xv1.x*w0.y + xv1.y*w1.y + xv1.z*w2.y + xv1.w*w3.y;
            a1.z += xv1.x*w0.z + xv1.y*w1.z + xv1.z*w2.z + xv1.w*w3.z;
            a1.w += xv1.x*w0.w + xv1.y*w1.w + xv1.z*w2.w + xv1.w*w3.w;
            a2.x += xv2.x*w0.x + xv2.y*w1.x + xv2.z*w2.x + xv2.w*w3.x;
            a2.y += xv2.x*w0.y + xv2.y*w1.y + xv2.z*w2.y + xv2.w*w3.y;
            a2.z += xv2.x*w0.z + xv2.y*w1.z + xv2.z*w2.z + xv2.w*w3.z;
            a2.w += xv2.x*w0.w + xv2.y*w1.w + xv2.z*w2.w + xv2.w*w3.w;
            a3.x += xv3.x*w0.x + xv3.y*w1.x + xv3.z*w2.x + xv3.w*w3.x;
            a3.y += xv3.x*w0.y + xv3.y*w1.y + xv3.z*w2.y + xv3.w*w3.y;
            a3.z += xv3.x*w0.z + xv3.y*w1.z + xv3.z*w2.z + xv3.w*w3.z;
            a3.w += xv3.x*w0.w + xv3.y*w1.w + xv3.z*w2.w + xv3.w*w3.w;
        }
        #pragma unroll
        for (int r = 0; r < 4; ++r) {
            int row = row0 + rb + r;
            if (row < n) {
                float4 acc = (r == 0) ? a0 : (r == 1) ? a1 : (r == 2) ? a2 : a3;
                if (sub == 0)
                    *(float4*)(qs1 + (size_t)row * 64 + j) = acc;
                else if (sub == 3)
                    *(float4*)(qs1 + (size_t)row * 64 + 32 + j) = acc;
                else {
                    unsigned u8 = __builtin_amdgcn_cvt_pk_fp8_f32(acc.x, acc.y, 0u, false);
                    u8 = __builtin_amdgcn_cvt_pk_fp8_f32(acc.z, acc.w, u8, true);
                    *(unsigned*)(kv1 + (size_t)row * 64 + ((sub == 1) ? 0 : 32) + j) = u8;
                }
            }
        }
        __syncthreads();
    }
}

// ================= conv2 projection (32 -> 4x16) ==========================
__global__ __launch_bounds__(256) void proj2_kernel(
    const float* __restrict__ h1,
    const float* __restrict__ Wq, const float* __restrict__ bq,
    const float* __restrict__ Wk, const float* __restrict__ bk,
    const float* __restrict__ Wv, const float* __restrict__ bv,
    const float* __restrict__ Ws, const float* __restrict__ bs,
    float* __restrict__ qs2, unsigned char* __restrict__ kv2, int n)
{
    __shared__ float Wl[32][64];
    __shared__ float bl[64];
    __shared__ float xl[4][32];
    for (int i = threadIdx.x; i < 32 * 64; i += 256) {
        int k = i >> 6, c = i & 63;
        int sub = c >> 4, j = c & 15;
        const float* W = (sub == 0) ? Wq : (sub == 1) ? Wk : (sub == 2) ? Wv : Ws;
        Wl[k][c] = W[k * 16 + j];
    }
    if (threadIdx.x < 64) {
        int c = threadIdx.x, sub = c >> 4, j = c & 15;
        const float* b = (sub == 0) ? bq : (sub == 1) ? bk : (sub == 2) ? bv : bs;
        bl[c] = b[j];
    }
    __syncthreads();
    int r = threadIdx.x >> 6, col = threadIdx.x & 63;
    int sub = col >> 4, j = col & 15;
    for (int row0 = blockIdx.x * 4; row0 < n; row0 += gridDim.x * 4) {
        int li = threadIdx.x;
        if (li < 128) {
            int rr = row0 + (li >> 5);
            if (rr < n) xl[li >> 5][li & 31] = h1[(size_t)rr * 32 + (li & 31)];
        }
        __syncthreads();
        int row = row0 + r;
        if (row < n) {
            float acc = bl[col];
            #pragma unroll
            for (int k = 0; k < 32; ++k) acc += xl[r][k] * Wl[k][col];
            if (sub == 0)       qs2[(size_t)row * 32 + j] = acc;
            else if (sub == 3)  qs2[(size_t)row * 32 + 16 + j] = acc;
            else {
                unsigned u8 = __builtin_amdgcn_cvt_pk_fp8_f32(acc, 0.f, 0u, false);
                kv2[(size_t)row * 32 + ((sub == 1) ? 0 : 16) + j] = (unsigned char)(u8 & 0xFF);
            }
        }
        __syncthreads();
    }
}

// ===== conv1 fused gather: degree-sorted, fp8 KV, 1-deep pipeline =========
__global__ __launch_bounds__(256) void gather_conv1(
    const int* __restrict__ row_ptr, const int* __restrict__ order,
    const int* __restrict__ col, const float* __restrict__ qs1,
    const unsigned char* __restrict__ kv1, float* __restrict__ h1, int n)
{
    int tid = blockIdx.x * 256 + threadIdx.x;
    if (tid >= n * HEADS) return;
    int node = order[tid >> 2], h = tid & 3;
    const float4* qp = (const float4*)(qs1 + (size_t)node * 64 + h * 8);
    float4 q0 = qp[0], q1 = qp[1];
    int start = row_ptr[node], d = row_ptr[node + 1] - start;
    float m = -INFINITY, s = 0.f;
    float a0x=0,a0y=0,a0z=0,a0w=0,a1x=0,a1y=0,a1z=0,a1w=0;
    uint2 ku = make_uint2(0,0), vu = make_uint2(0,0);
    if (d > 0) {
        const unsigned char* b0 = kv1 + (size_t)col[start] * 64;
        ku = *(const uint2*)(b0 + h * 8);
        vu = *(const uint2*)(b0 + 32 + h * 8);
    }
    for (int i = 0; i < d; ++i) {
        uint2 kn = ku, vn = vu;
        if (i + 1 < d) {
            const unsigned char* nb = kv1 + (size_t)col[start + i + 1] * 64;
            kn = *(const uint2*)(nb + h * 8);
            vn = *(const uint2*)(nb + 32 + h * 8);
        }
        floatx2 k01 = __builtin_amdgcn_cvt_pk_f32_fp8(ku.x, false);
        floatx2 k23 = __builtin_amdgcn_cvt_pk_f32_fp8(ku.x, true);
        floatx2 k45 = __builtin_amdgcn_cvt_pk_f32_fp8(ku.y, false);
        floatx2 k67 = __builtin_amdgcn_cvt_pk_f32_fp8(ku.y, true);
        float a = (q0.x*k01.x + q0.y*k01.y + q0.z*k23.x + q0.w*k23.y
                 + q1.x*k45.x + q1.y*k45.y + q1.z*k67.x + q1.w*k67.y)
                * 0.35355339059327373f;  // 1/sqrt(8)
        float mn = fmaxf(m, a);
        float corr = __expf(m - mn);   // first iter: exp(-inf)=0
        float ea = __expf(a - mn);
        s = s * corr + ea;
        floatx2 v01 = __builtin_amdgcn_cvt_pk_f32_fp8(vu.x, false);
        floatx2 v23 = __builtin_amdgcn_cvt_pk_f32_fp8(vu.x, true);
        floatx2 v45 = __builtin_amdgcn_cvt_pk_f32_fp8(vu.y, false);
        floatx2 v67 = __builtin_amdgcn_cvt_pk_f32_fp8(vu.y, true);
        a0x = a0x*corr + ea*v01.x; a0y = a0y*corr + ea*v01.y;
        a0z = a0z*corr + ea*v23.x; a0w = a0w*corr + ea*v23.y;
        a1x = a1x*corr + ea*v45.x; a1y = a1y*corr + ea*v45.y;
        a1z = a1z*corr + ea*v67.x; a1w = a1w*corr + ea*v67.y;
        m = mn;
        ku = kn; vu = vn;
    }
    float inv = 1.f / (s + EPS);
    const float* sk = qs1 + (size_t)node * 64 + 32 + h * 8;
    float4 o0, o1;
    o0.x = fmaxf(a0x*inv + sk[0], 0.f); o0.y = fmaxf(a0y*inv + sk[1], 0.f);
    o0.z = fmaxf(a0z*inv + sk[2], 0.f); o0.w = fmaxf(a0w*inv + sk[3], 0.f);
    o1.x = fmaxf(a1x*inv + sk[4], 0.f); o1.y = fmaxf(a1y*inv + sk[5], 0.f);
    o1.z = fmaxf(a1z*inv + sk[6], 0.f); o1.w = fmaxf(a1w*inv + sk[7], 0.f);
    float4* op = (float4*)(h1 + (size_t)node * 32 + h * 8);
    op[0] = o0; op[1] = o1;
}

// ===== conv2 fused gather (C=4), degree-sorted order, fp8 KV ==============
__global__ __launch_bounds__(256) void gather_conv2(
    const int* __restrict__ row_ptr, const int* __restrict__ order,
    const int* __restrict__ col, const float* __restrict__ qs2,
    const unsigned char* __restrict__ kv2, float* __restrict__ h2, int n)
{
    int tid = blockIdx.x * 256 + threadIdx.x;
    if (tid >= n * HEADS) return;
    int node = order[tid >> 2], h = tid & 3;
    float4 q = *(const float4*)(qs2 + (size_t)node * 32 + h * 4);
    int start = row_ptr[node], d = row_ptr[node + 1] - start;
    float m = -INFINITY, s = 0.f;
    float ax=0, ay=0, az=0, aw=0;
    unsigned ku = 0, vu = 0;
    if (d > 0) {
        const unsigned char* b0 = kv2 + (size_t)col[start] * 32;
        ku = *(const unsigned*)(b0 + h * 4);
        vu = *(const unsigned*)(b0 + 16 + h * 4);
    }
    for (int i = 0; i < d; ++i) {
        unsigned kn = ku, vn = vu;
        if (i + 1 < d) {
            const unsigned char* nb = kv2 + (size_t)col[start + i + 1] * 32;
            kn = *(const unsigned*)(nb + h * 4);
            vn = *(const unsigned*)(nb + 16 + h * 4);
        }
        floatx2 k01 = __builtin_amdgcn_cvt_pk_f32_fp8(ku, false);
        floatx2 k23 = __builtin_amdgcn_cvt_pk_f32_fp8(ku, true);
        float a = (q.x*k01.x + q.y*k01.y + q.z*k23.x + q.w*k23.y) * 0.5f; // 1/sqrt(4)
        float mn = fmaxf(m, a);
        float corr = __expf(m - mn);
        float ea = __expf(a - mn);
        s = s * corr + ea;
        floatx2 v01 = __builtin_amdgcn_cvt_pk_f32_fp8(vu, false);
        floatx2 v23 = __builtin_amdgcn_cvt_pk_f32_fp8(vu, true);
        ax = ax*corr + ea*v01.x; ay = ay*corr + ea*v01.y;
        az = az*corr + ea*v23.x; aw = aw*corr + ea*v23.y;
        m = mn;
        ku = kn; vu = vn;
    }
    float inv = 1.f / (s + EPS);
    const float* sk = qs2 + (size_t)node * 32 + 16 + h * 4;
    float4 o;
    o.x = fmaxf(ax*inv + sk[0], 0.f);
    o.y = fmaxf(ay*inv + sk[1], 0.f);
    o.z = fmaxf(az*inv + sk[2], 0.f);
    o.w = fmaxf(aw*inv + sk[3], 0.f);
    *(float4*)(h2 + (size_t)node * 16 + h * 4) = o;
}

// ====== mean-pool accumulation over h2 (block-local reduce, batch sorted) =
__global__ __launch_bounds__(256) void pool_kernel(
    const float* __restrict__ h2, const int* __restrict__ batch,
    float* __restrict__ pooled, float* __restrict__ cnt, int n)
{
    __shared__ float acc[16];
    __shared__ int bShared;
    __shared__ int uniform;
    int node0 = blockIdx.x * 16;
    int t = threadIdx.x;
    int node = node0 + (t >> 4), j = t & 15;
    if (t == 0) {
        int bFirst = batch[node0];
        int bLast = batch[min(node0 + 15, n - 1)];
        bShared = bFirst;
        uniform = (bFirst == bLast);
    }
    if (t < 16) acc[t] = 0.f;
    __syncthreads();
    bool active = node < n;
    float val = active ? h2[(size_t)node * 16 + j] : 0.f;
    if (uniform) {
        if (active) atomicAdd(&acc[j], val);
        __syncthreads();
        int nlocal = min(16, n - node0);
        if (t < 16) atomicAdd(pooled + bShared * 16 + t, acc[t]);
        if (t == 0) atomicAdd(cnt + bShared, (float)nlocal);
    } else {
        if (active) {
            int b = batch[node];
            atomicAdd(pooled + b * 16 + j, val);
            if (j == 0) atomicAdd(cnt + b, 1.f);
        }
    }
}

// ================= final FC on pooled [64,16] -> [64,10] ==================
__global__ void fc_kernel(
    const float* __restrict__ pooled, const float* __restrict__ cnt,
    const float* __restrict__ Wfc, const float* __restrict__ bfc,
    float* __restrict__ out)
{
    int t = threadIdx.x;
    if (t < 64 * 10) {
        int b = t / 10, o = t % 10;
        float c = fmaxf(cnt[b], 1.0f);
        float acc = bfc[o];
        #pragma unroll
        for (int k = 0; k < 16; ++k)
            acc += (pooled[b * 16 + k] / c) * Wfc[k * 10 + o];
        out[t] = acc;
    }
}

extern "C" void kernel_launch(void* const* d_in, const int* in_sizes, int n_in,
                              void* d_out, int out_size, void* d_ws, size_t ws_size,
                              hipStream_t stream) {
    const float* x     = (const float*)d_in[0];
    const int*   ei    = (const int*)d_in[1];
    const int*   batch = (const int*)d_in[2];
    const float* Wq1 = (const float*)d_in[3],  *bq1 = (const float*)d_in[4];
    const float* Wk1 = (const float*)d_in[5],  *bk1 = (const float*)d_in[6];
    const float* Wv1 = (const float*)d_in[7],  *bv1 = (const float*)d_in[8];
    const float* Ws1 = (const float*)d_in[9],  *bs1 = (const float*)d_in[10];
    const float* Wq2 = (const float*)d_in[11], *bq2 = (const float*)d_in[12];
    const float* Wk2 = (const float*)d_in[13], *bk2 = (const float*)d_in[14];
    const float* Wv2 = (const float*)d_in[15], *bv2 = (const float*)d_in[16];
    const float* Ws2 = (const float*)d_in[17], *bs2 = (const float*)d_in[18];
    const float* Wfc = (const float*)d_in[19], *bfc = (const float*)d_in[20];

    int N = in_sizes[0] / 128;
    int E = in_sizes[1] / 2;
    int rdiv = (N + NR - 1) / NR;            // 391 nodes per range
    float rinv = 1.0f / (float)rdiv;
    int NB = (E + EPB - 1) / EPB;            // scatter blocks

    // ---- workspace layout ----
    float* ws = (float*)d_ws;
    float* qs1    = ws;                                   // N*64 f  (q|s conv1)
    float* h1     = qs1 + (size_t)N * 64;                 // N*32 f  (aliased rsrc)
    float* h2     = h1 + (size_t)N * 32;                  // N*16 f  (aliased rdst lo)
    float* qs2    = h2 + (size_t)N * 16;                  // N*32 f  (rdst overflow)
    float* pooled = qs2 + (size_t)N * 32;                 // 1024 f
    float* cnt    = pooled + 1024;                        // 64 f
    unsigned char* kv1 = (unsigned char*)(cnt + 64);      // N*64 fp8 (64B/node)
    unsigned char* kv2 = kv1 + (size_t)N * 64;            // N*32 fp8 (32B/node)
    int* deg     = (int*)(kv2 + (size_t)N * 32);          // N
    int* row_ptr = deg + N;                               // N+1 (sentinel)
    int* rstart  = row_ptr + N + 1;                       // NR+1
    int* qtot    = rstart + NR + 1;                       // NR (reused as dsort tot)
    int* col     = qtot + NR;                             // E
    int* order   = col + E;                               // N
    int* pcnt    = order + N;                             // NB*NR
    int* phd     = pcnt + (size_t)NB * NR;                // NR*256
    int* rsrc = (int*)h1;                                 // E ints (N*32 == E)
    int* rdst = (int*)h2;                                 // E ints (spills into qs2)

    // zero: pooled + cnt accumulators only (everything else fully written)
    hipMemsetAsync(pooled, 0, (1024 + 64) * sizeof(float), stream);

    int ngrid = (N * HEADS + 255) / 256;

    // ---- CSR build + fused degree sort (LDS atomics only) ----
    scatter_count<<<NB, 256, 0, stream>>>(ei, E, rdiv, rinv, pcnt);
    qprefix<<<NR, 256, 0, stream>>>(pcnt, NB, qtot);
    qscan<<<1, NR, 0, stream>>>(qtot, rstart);
    scatter_place<<<NB, 256, 0, stream>>>(ei, E, rdiv, rinv, pcnt, rstart, rsrc, rdst);
    deg_range<<<NR, 256, 0, stream>>>(rdst, rstart, deg, row_ptr, phd, N, rdiv, E);
    dsort_scanA<<<NR, 256, 0, stream>>>(phd, qtot);
    dsort_scanB<<<1, 256, 0, stream>>>(qtot);
    dsort_addC<<<NR, 256, 0, stream>>>(phd, qtot);
    place_range<<<NR, 256, 0, stream>>>(rsrc, rdst, rstart, row_ptr, deg, phd, col, order, N, rdiv);

    // ---- conv1 ----
    proj1_kernel<<<2048, 256, 0, stream>>>(x, Wq1, bq1, Wk1, bk1, Wv1, bv1, Ws1, bs1, qs1, kv1, N);
    gather_conv1<<<ngrid, 256, 0, stream>>>(row_ptr, order, col, qs1, kv1, h1, N);

    // ---- conv2 ----
    proj2_kernel<<<1024, 256, 0, stream>>>(h1, Wq2, bq2, Wk2, bk2, Wv2, bv2, Ws2, bs2, qs2, kv2, N);
    gather_conv2<<<ngrid, 256, 0, stream>>>(row_ptr, order, col, qs2, kv2, h2, N);

    // ---- pool + fc ----
    pool_kernel<<<(N + 15) / 16, 256, 0, stream>>>(h2, batch, pooled, cnt, N);
    fc_kernel<<<1, 640, 0, stream>>>(pooled, cnt, Wfc, bfc, (float*)d_out);
}